// Round 14
// baseline (3518.808 us; speedup 1.0000x reference)
//
#include <hip/hip_runtime.h>
#include <math.h>

// TransformerCell — 4-hop dataflow (R13) + DIRECT-FIRE chunks.
// f-vector exchanges now 1 value/chunk (1024 chunks x 8 replicas): after wred
// every lane holds the row value, so lanes 0-7 fire all 8 replicas with one
// store issue — no producer-side __syncthreads, no LDS round trip. Consumers
// poll 2 chunks/thread (tid, tid+512) in one combined sweep; stage sX[tid]
// (stride-1, conflict-free). aC (logit gather) unchanged (256 chunks).
// Everything else identical to R13 (linear recurrences for d/U/z, rMT-register
// GWORK, parity gC routing, tags memset per launch).

#define NTHR 512
#define NBLK 256

#define B_AC   4096      /* aC  [8][256] chunks  -> ends 36864 */
#define B_SM   36864     /* smC [8][1024] 1-val chunks -> 167936 */
#define B_C    167936    /* cCh [8][1024] -> 299008 */
#define B_F    299008    /* fCh [8][1024] -> 430080 */
#define B_ZM   430080    /* zmC [8][1024] -> 561152 */
#define B_GC   561152    /* gC [2][512] -> 577536 */
#define B_DV   577536    /* dVec float[2][1024] */

typedef int i4 __attribute__((ext_vector_type(4)));

__device__ __forceinline__ float i2f(int x) { return __int_as_float(x); }
__device__ __forceinline__ int f2i(float x) { return __float_as_int(x); }

__device__ __forceinline__ void astore(float* p, float v) {
  __hip_atomic_store(p, v, __ATOMIC_RELAXED, __HIP_MEMORY_SCOPE_AGENT);
}
__device__ __forceinline__ float2 aload2(const float* p) {
  double d = __hip_atomic_load((double*)p, __ATOMIC_RELAXED, __HIP_MEMORY_SCOPE_AGENT);
  return __builtin_bit_cast(float2, d);
}
__device__ __forceinline__ int aloadI(const int* p) {
  return __hip_atomic_load((int*)p, __ATOMIC_RELAXED, __HIP_MEMORY_SCOPE_AGENT);
}
__device__ __forceinline__ int afaddI(int* p) {
  return __hip_atomic_fetch_add(p, 1, __ATOMIC_RELAXED, __HIP_MEMORY_SCOPE_AGENT);
}

__device__ __forceinline__ i4 poll16(const i4* p, int tag) {
  i4 v;
  for (;;) {
    asm volatile("global_load_dwordx4 %0, %1, off sc0 sc1\n\ts_waitcnt vmcnt(0)"
                 : "=&v"(v) : "v"(p) : "memory");
    if (v.w == tag) return v;
    __builtin_amdgcn_s_sleep(1);
  }
}
__device__ __forceinline__ void store16(i4* p, i4 v) {
  asm volatile("global_store_dwordx4 %0, %1, off sc0 sc1" :: "v"(p), "v"(v) : "memory");
}
// combined 2-chunk poll (chunks tid, tid+512) -> dst[tid], dst[tid+512]
__device__ __forceinline__ void pollf(const i4* base, int tag, int tid, float* dst) {
  i4 a, b;
  int got = 0;
  for (;;) {
    if (!(got & 1))
      asm volatile("global_load_dwordx4 %0, %1, off sc0 sc1"
                   : "=v"(a) : "v"(base + tid) : "memory");
    if (!(got & 2))
      asm volatile("global_load_dwordx4 %0, %1, off sc0 sc1"
                   : "=v"(b) : "v"(base + tid + 512) : "memory");
    asm volatile("s_waitcnt vmcnt(0)" ::: "memory");
    if (!(got & 1) && a.w == tag) { got |= 1; dst[tid] = i2f(a.x); }
    if (!(got & 2) && b.w == tag) { got |= 2; dst[tid + 512] = i2f(b.x); }
    if (got == 3) return;
    __builtin_amdgcn_s_sleep(1);
  }
}

__device__ __forceinline__ float wred(float v) {
#pragma unroll
  for (int o = 1; o < 64; o <<= 1) v += __shfl_xor(v, o, 64);
  return v;
}
__device__ __forceinline__ void wred2(float& a, float& b) {
#pragma unroll
  for (int o = 1; o < 64; o <<= 1) { a += __shfl_xor(a, o, 64); b += __shfl_xor(b, o, 64); }
}
__device__ __forceinline__ void wred3(float& a, float& b, float& c) {
#pragma unroll
  for (int o = 1; o < 64; o <<= 1) {
    a += __shfl_xor(a, o, 64); b += __shfl_xor(b, o, 64); c += __shfl_xor(c, o, 64);
  }
}
__device__ __forceinline__ float wmax(float v) {
#pragma unroll
  for (int o = 1; o < 64; o <<= 1) v = fmaxf(v, __shfl_xor(v, o, 64));
  return v;
}
__device__ __forceinline__ float lrelu(float x) { return x > 0.f ? x : 0.01f * x; }

__device__ __forceinline__ void gsync1(int* bar, int bid, int tid, int lane) {
  asm volatile("" ::: "memory");
  __builtin_amdgcn_s_waitcnt(0);
  __syncthreads();
  if (tid == 0) afaddI(bar + (bid & 7) * 16);
  if (tid < 64) {
    for (;;) {
      int v = (lane < 8) ? aloadI(bar + lane * 16) : 0x7fffffff;
      if (__all(v >= 32)) break;
      __builtin_amdgcn_s_sleep(2);
    }
  }
  __syncthreads();
  asm volatile("" ::: "memory");
}

__global__ void __launch_bounds__(NTHR) tcell(
    const float* __restrict__ mu, const float* __restrict__ z0,
    const float* __restrict__ W1, const float* __restrict__ W2, const float* __restrict__ W3,
    const float* __restrict__ p_in_w, const float* __restrict__ p_in_b,
    const float* __restrict__ p_h0_w, const float* __restrict__ p_h0_b,
    const float* __restrict__ p_h1_w, const float* __restrict__ p_h1_b,
    const float* __restrict__ p_out_w, const float* __restrict__ p_out_b,
    const float* __restrict__ m_in_w, const float* __restrict__ m_in_b,
    const float* __restrict__ m_h0_w, const float* __restrict__ m_h0_b,
    const float* __restrict__ m_h1_w, const float* __restrict__ m_h1_b,
    const float* __restrict__ m_out_w, const float* __restrict__ m_out_b,
    float* __restrict__ Z, float* __restrict__ ws) {
  const int tid = threadIdx.x;
  const int bid = blockIdx.x;
  const int lane = tid & 63;
  const int wave = tid >> 6;            // 0..7
  const int r = 4 * bid + (wave & 3);
  const int rep = bid & 7;

  char* wsb = (char*)ws;
  int* bar = (int*)wsb;
  i4* aC  = (i4*)(wsb + B_AC);
  i4* smC = (i4*)(wsb + B_SM);
  i4* cCh = (i4*)(wsb + B_C);
  i4* fCh = (i4*)(wsb + B_F);
  i4* zmC = (i4*)(wsb + B_ZM);
  i4* gC  = (i4*)(wsb + B_GC);
  float* dVec = (float*)(wsb + B_DV);
  i4* aCr  = aC  + rep * 256;
  i4* smCr = smC + rep * 1024;
  i4* cChr = cCh + rep * 1024;
  i4* fChr = fCh + rep * 1024;
  i4* zmCr = zmC + rep * 1024;

  __shared__ float sX[1024], sDv[1024];
  __shared__ float sLg[256], sNp[256], sPp[256], sR[256];
  __shared__ float sBigB[4][1024], sBigW[4][1024];
  __shared__ float sU[4][257];
  __shared__ float shD[4], shDp[4], shZ[4], shG[4], shGv[4];

  // ---- P0: waves 0-3 build B=W1@W2, W~=m_in_w@W3 rows (regs); wave 4: p_in
  float4 rB4[4], rW4[4];
  if (wave < 4) {
#pragma unroll
    for (int q = 0; q < 4; ++q) {
      rB4[q] = make_float4(0.f, 0.f, 0.f, 0.f);
      rW4[q] = make_float4(0.f, 0.f, 0.f, 0.f);
    }
    const float* __restrict__ w1r = W1 + (size_t)r * 512;
    const float* __restrict__ mir = m_in_w + (size_t)r * 512;
    for (int k = 0; k < 512; k += 2) {
      float w1a = w1r[k], w1b = w1r[k + 1];
      float mia = mir[k], mib = mir[k + 1];
      const float* w2a = W2 + (size_t)k * 1024 + 4 * lane;
      const float* w3a = W3 + (size_t)k * 1024 + 4 * lane;
#pragma unroll
      for (int q = 0; q < 4; ++q) {
        float4 a0 = *(const float4*)(w2a + 256 * q);
        float4 a1 = *(const float4*)(w2a + 1024 + 256 * q);
        float4 b0 = *(const float4*)(w3a + 256 * q);
        float4 b1 = *(const float4*)(w3a + 1024 + 256 * q);
        rB4[q].x = fmaf(w1a, a0.x, fmaf(w1b, a1.x, rB4[q].x));
        rB4[q].y = fmaf(w1a, a0.y, fmaf(w1b, a1.y, rB4[q].y));
        rB4[q].z = fmaf(w1a, a0.z, fmaf(w1b, a1.z, rB4[q].z));
        rB4[q].w = fmaf(w1a, a0.w, fmaf(w1b, a1.w, rB4[q].w));
        rW4[q].x = fmaf(mia, b0.x, fmaf(mib, b1.x, rW4[q].x));
        rW4[q].y = fmaf(mia, b0.y, fmaf(mib, b1.y, rW4[q].y));
        rW4[q].z = fmaf(mia, b0.z, fmaf(mib, b1.z, rW4[q].z));
        rW4[q].w = fmaf(mia, b0.w, fmaf(mib, b1.w, rW4[q].w));
      }
    }
  } else if (wave == 4) {
#pragma unroll
    for (int j = 0; j < 4; ++j) {
      int row = 4 * bid + j;
      float acc = p_in_w[(size_t)row * 64 + lane] * mu[lane];
      acc = wred(acc);
      float vv = lrelu(acc + p_in_b[row]);
      if (lane < 8) {
        i4 c; c.x = f2i(vv); c.y = 0; c.z = 0; c.w = 1;
        store16(smC + lane * 1024 + row, c);
      }
    }
  }

#define MVP(WPTR, BPTR, ACT, INC, INTAG, OUTC, OUTTAG)                         \
  pollf((INC), (INTAG), tid, sX);                                              \
  __syncthreads();                                                             \
  if (wave < 4) {                                                              \
    const float* w = (WPTR) + (size_t)r * 1024 + 4 * lane;                     \
    float acc = 0.f;                                                           \
    _Pragma("unroll")                                                          \
    for (int q = 0; q < 4; ++q) {                                              \
      float4 wf = *(const float4*)(w + 256 * q);                               \
      float4 xf = *(const float4*)(sX + 4 * lane + 256 * q);                   \
      acc = fmaf(wf.x, xf.x, acc); acc = fmaf(wf.y, xf.y, acc);                \
      acc = fmaf(wf.z, xf.z, acc); acc = fmaf(wf.w, xf.w, acc);                \
    }                                                                          \
    acc = wred(acc);                                                           \
    float vv = acc + (BPTR)[r];                                                \
    if (ACT) vv = lrelu(vv);                                                   \
    if (lane < 8) {                                                            \
      i4 c; c.x = f2i(vv); c.y = 0; c.z = 0; c.w = (OUTTAG);                   \
      store16((OUTC) + lane * 1024 + r, c);                                    \
    }                                                                          \
  }

  // ---- P1..P2 (MLP_p chain)
  MVP(p_h0_w, p_h0_b, 1, smCr, 1, cCh, 1)
  MVP(p_h1_w, p_h1_b, 1, cChr, 1, fCh, 1)
  // ---- P3: z_minus -> zmC + Z[0]; Z[1] = z0
  pollf(fChr, 1, tid, sX);
  __syncthreads();
  if (wave < 4) {
    const float* w = p_out_w + (size_t)r * 1024 + 4 * lane;
    float acc = 0.f;
#pragma unroll
    for (int q = 0; q < 4; ++q) {
      float4 wf = *(const float4*)(w + 256 * q);
      float4 xf = *(const float4*)(sX + 4 * lane + 256 * q);
      acc = fmaf(wf.x, xf.x, acc); acc = fmaf(wf.y, xf.y, acc);
      acc = fmaf(wf.z, xf.z, acc); acc = fmaf(wf.w, xf.w, acc);
    }
    acc = wred(acc);
    float vv = acc + p_out_b[r];
    if (lane < 8) {
      i4 c; c.x = f2i(vv); c.y = 0; c.z = 0; c.w = 1;
      store16(zmC + lane * 1024 + r, c);
    }
    if (lane == 8) astore(Z + r, vv);
  }
  if (bid < 2) Z[1024 + bid * 512 + tid] = z0[bid * 512 + tid];

  // ---- P4: z_minus -> sDv; z0 -> sX; append rows 0 and 1
  float d0_w = 0.f, d_prev = 0.f, z_prev = 0.f;
  pollf(zmCr, 1, tid, sDv);
  { float2 a = *(const float2*)(z0 + 2 * tid); sX[2*tid] = a.x; sX[2*tid+1] = a.y; }
  __syncthreads();
  if (wave < 4) {
    float aD = 0.f, aU = 0.f, bD = 0.f, bU = 0.f;
#pragma unroll
    for (int q = 0; q < 4; ++q) {
      float4 zm = *(const float4*)(sDv + 4 * lane + 256 * q);
      float4 z1 = *(const float4*)(sX + 4 * lane + 256 * q);
      aD = fmaf(rB4[q].x, zm.x, aD); aD = fmaf(rB4[q].y, zm.y, aD);
      aD = fmaf(rB4[q].z, zm.z, aD); aD = fmaf(rB4[q].w, zm.w, aD);
      aU = fmaf(rW4[q].x, zm.x, aU); aU = fmaf(rW4[q].y, zm.y, aU);
      aU = fmaf(rW4[q].z, zm.z, aU); aU = fmaf(rW4[q].w, zm.w, aU);
      bD = fmaf(rB4[q].x, z1.x, bD); bD = fmaf(rB4[q].y, z1.y, bD);
      bD = fmaf(rB4[q].z, z1.z, bD); bD = fmaf(rB4[q].w, z1.w, bD);
      bU = fmaf(rW4[q].x, z1.x, bU); bU = fmaf(rW4[q].y, z1.y, bU);
      bU = fmaf(rW4[q].z, z1.z, bU); bU = fmaf(rW4[q].w, z1.w, bU);
    }
    wred2(aD, aU); wred2(bD, bU);
    d0_w = aD; d_prev = bD; z_prev = z0[r];
    if (lane == 0) {
      sU[wave][0] = aU; sU[wave][1] = bU;
      astore(dVec + 1024 + r, aD);   // dVec[1] = d_0
      astore(dVec + r, bD);          // dVec[0] = d_1
    }
  }
  gsync1(bar, bid, tid, lane);

  // ---- rMT: own row of M^T (column r of m_out_w) — one-time strided read
  float4 rMT[4];
  if (wave < 4) {
#pragma unroll
    for (int q = 0; q < 4; ++q) {
      int m0 = 4 * lane + 256 * q;
      rMT[q].x = m_out_w[(size_t)(m0 + 0) * 1024 + r];
      rMT[q].y = m_out_w[(size_t)(m0 + 1) * 1024 + r];
      rMT[q].z = m_out_w[(size_t)(m0 + 2) * 1024 + r];
      rMT[q].w = m_out_w[(size_t)(m0 + 3) * 1024 + r];
    }
  }

  // per-block state
  float lgreg = 0.f, dmob = 0.f;
  float4 G4 = make_float4(0.f, 0.f, 0.f, 0.f);

#define GWORK(PAR, TAG, ROWID)                                                 \
  { float2 a = aload2(dVec + (PAR) * 1024 + 2 * tid);                          \
    sDv[2*tid] = a.x; sDv[2*tid+1] = a.y; }                                    \
  __syncthreads();                                                             \
  if (wave < 4) {                                                              \
    float acc = 0.f;                                                           \
    _Pragma("unroll")                                                          \
    for (int q = 0; q < 4; ++q) {                                              \
      float4 d4 = *(const float4*)(sDv + 4 * lane + 256 * q);                  \
      acc = fmaf(rMT[q].x, d4.x, acc); acc = fmaf(rMT[q].y, d4.y, acc);        \
      acc = fmaf(rMT[q].z, d4.z, acc); acc = fmaf(rMT[q].w, d4.w, acc);        \
    }                                                                          \
    acc = wred(acc);                                                           \
    if (lane == 0) shGv[wave] = acc;                                           \
  }                                                                            \
  { float pd = sDv[tid] * m_out_b[tid] + sDv[tid+512] * m_out_b[tid+512];      \
    sX[tid] = pd; }                                                            \
  __syncthreads();                                                             \
  if (wave == 0) {                                                             \
    float s = sX[lane] + sX[lane+64] + sX[lane+128] + sX[lane+192]             \
            + sX[lane+256] + sX[lane+320] + sX[lane+384] + sX[lane+448];       \
    s = wred(s);                                                               \
    if (bid == (ROWID)) dmob = s;                                              \
    if (lane < 2) {                                                            \
      i4 c; c.x = f2i(shGv[2*lane]); c.y = f2i(shGv[2*lane+1]); c.z = 0;       \
      c.w = (TAG);                                                             \
      store16(gC + (PAR) * 512 + 2 * bid + lane, c);                           \
    }                                                                          \
  }

  // G-work for row 0 (appended in prologue)
  GWORK(1, 1, 0)

  // ---- precompute rBM=(B@M) row, rWM=(W~@M) row, rMo=M row, biases
  float4 rBM[4], rWM[4], rMo[4];
  float bmob = 0.f, wmob = 0.f, mob_own = 0.f;
  if (wave < 4) {
#pragma unroll
    for (int q = 0; q < 4; ++q) {
      *(float4*)(&sBigB[wave][4 * lane + 256 * q]) = rB4[q];
      *(float4*)(&sBigW[wave][4 * lane + 256 * q]) = rW4[q];
      rBM[q] = make_float4(0.f, 0.f, 0.f, 0.f);
      rWM[q] = make_float4(0.f, 0.f, 0.f, 0.f);
    }
  }
  __syncthreads();
  if (wave < 4) {
    for (int m = 0; m < 1024; ++m) {
      float bB = sBigB[wave][m], bW = sBigW[wave][m];
      float mb = m_out_b[m];
      bmob = fmaf(bB, mb, bmob); wmob = fmaf(bW, mb, wmob);
      const float* mo = m_out_w + (size_t)m * 1024 + 4 * lane;
#pragma unroll
      for (int q = 0; q < 4; ++q) {
        float4 m4 = *(const float4*)(mo + 256 * q);
        rBM[q].x = fmaf(bB, m4.x, rBM[q].x); rBM[q].y = fmaf(bB, m4.y, rBM[q].y);
        rBM[q].z = fmaf(bB, m4.z, rBM[q].z); rBM[q].w = fmaf(bB, m4.w, rBM[q].w);
        rWM[q].x = fmaf(bW, m4.x, rWM[q].x); rWM[q].y = fmaf(bW, m4.y, rWM[q].y);
        rWM[q].z = fmaf(bW, m4.z, rWM[q].z); rWM[q].w = fmaf(bW, m4.w, rWM[q].w);
      }
    }
#pragma unroll
    for (int q = 0; q < 4; ++q)
      rMo[q] = *(const float4*)(m_out_w + (size_t)r * 1024 + 4 * lane + 256 * q);
    mob_own = m_out_b[r];
  }

  // ---- main recurrence: A' -> SM -> C -> D (+offpath G)
  for (int t = 2; t <= 256; ++t) {
    // ---------- Phase A' ----------
    if (t == 2) {
      if (wave < 4 && lane == 0) { shD[wave] = d_prev; shDp[wave] = d0_w; shZ[wave] = z_prev; }
      __syncthreads();
    } else {
      pollf(fChr, t - 1, tid, sX);
      __syncthreads();
      if (wave < 4) {
        float dB = 0.f, dW = 0.f, dM = 0.f;
#pragma unroll
        for (int q = 0; q < 4; ++q) {
          float4 xf = *(const float4*)(sX + 4 * lane + 256 * q);
          dB = fmaf(rBM[q].x, xf.x, dB); dB = fmaf(rBM[q].y, xf.y, dB);
          dB = fmaf(rBM[q].z, xf.z, dB); dB = fmaf(rBM[q].w, xf.w, dB);
          dW = fmaf(rWM[q].x, xf.x, dW); dW = fmaf(rWM[q].y, xf.y, dW);
          dW = fmaf(rWM[q].z, xf.z, dW); dW = fmaf(rWM[q].w, xf.w, dW);
          dM = fmaf(rMo[q].x, xf.x, dM); dM = fmaf(rMo[q].y, xf.y, dM);
          dM = fmaf(rMo[q].z, xf.z, dM); dM = fmaf(rMo[q].w, xf.w, dM);
        }
        wred3(dB, dW, dM);
        float d_new = d_prev + dB + bmob;
        float U_new = sU[wave][t - 2] + dW + wmob;
        float z_new = z_prev + dM + mob_own;
        if (lane == 0) {
          sU[wave][t - 1] = U_new;
          astore(Z + (size_t)(t - 1) * 1024 + r, z_new);
          astore(dVec + (t & 1) * 1024 + r, d_new);
          shD[wave] = d_new; shDp[wave] = d_prev; shZ[wave] = z_new;
        }
        __builtin_amdgcn_s_waitcnt(0);   // drain d/Z stores before aC evidences them
        d_prev = d_new; z_prev = z_new;
      } else {
        int u = tid - 256;
        float gp = G4.x * sX[4*u] + G4.y * sX[4*u+1] + G4.z * sX[4*u+2] + G4.w * sX[4*u+3];
        gp = wred(gp);
        if (lane == 0) shG[wave - 4] = gp;
      }
      __syncthreads();
    }
    if (wave == 0) {
      float np = shD[0]*shZ[0] + shD[1]*shZ[1] + shD[2]*shZ[2] + shD[3]*shZ[3];
      float pp = shDp[0]*shZ[0] + shDp[1]*shZ[1] + shDp[2]*shZ[2] + shDp[3]*shZ[3];
      if (t >= 3 && bid <= t - 3)
        lgreg += shG[0] + shG[1] + shG[2] + shG[3] + dmob;
      if (lane < 8) {
        i4 c; c.x = f2i(lgreg); c.y = f2i(np); c.z = f2i(pp); c.w = t;
        store16(aC + lane * 256 + bid, c);
      }
    }

    // ---------- Phase SM ----------
    if (tid < 256) {
      i4 v = poll16(aCr + tid, t);
      sLg[tid] = i2f(v.x); sNp[tid] = i2f(v.y); sPp[tid] = i2f(v.z);
    }
    __syncthreads();
    if (wave == 0) {
      float ns = sNp[lane] + sNp[lane+64] + sNp[lane+128] + sNp[lane+192];
      float ps = sPp[lane] + sPp[lane+64] + sPp[lane+128] + sPp[lane+192];
      wred2(ns, ps);
      if (bid == t - 2) lgreg = ps;      // capture (unscaled)
      float l[4]; float mx = -1e30f;
#pragma unroll
      for (int j = 0; j < 4; ++j) {
        int i = lane + 64 * j;
        float li = -1e30f;
        if (i <= t - 3) li = sLg[i] * 0.03125f;
        else if (i == t - 2) li = ps * 0.03125f;
        else if (i == t - 1) li = ns * 0.03125f;
        l[j] = li; mx = fmaxf(mx, li);
      }
      mx = wmax(mx);
      float m = fmaxf(mx, 0.f);
      float e[4], es = 0.f;
#pragma unroll
      for (int j = 0; j < 4; ++j) {
        int i = lane + 64 * j;
        e[j] = (i <= t - 1) ? __expf(l[j] - m) : 0.f;
        es += e[j];
      }
      es = wred(es);
      float inv = 1.f / (es + (float)(257 - t) * __expf(-m));
#pragma unroll
      for (int j = 0; j < 4; ++j) sR[lane + 64 * j] = e[j] * inv;
    }
    __syncthreads();
    if (wave < 4) {
      float acc = 0.f;
#pragma unroll
      for (int j = 0; j < 4; ++j) {
        int i = lane + 64 * j;
        if (i <= t - 1) acc = fmaf(sR[i], sU[wave][i], acc);
      }
      acc = wred(acc);
      float vv = lrelu(acc + m_in_b[r]);
      if (lane < 8) {
        i4 c; c.x = f2i(vv); c.y = 0; c.z = 0; c.w = t;
        store16(smC + lane * 1024 + r, c);
      }
    }

    // ---------- Phase C ----------
    MVP(m_h0_w, m_h0_b, 1, smCr, t, cCh, t)

    // ---------- Phase D (fires f3) ----------
    MVP(m_h1_w, m_h1_b, 1, cChr, t, fCh, t)

    // ---------- off-path: G work for row t-1 ----------
    if (t <= 254) {
      GWORK((t & 1), t, t - 1)
    }
    // ---------- off-path: collect own G (row=bid, fired at step bid+1) ----------
    if (t == bid + 2 && bid <= 253) {
      if (tid >= 256) {
        int u = tid - 256;
        const i4* gbase = gC + ((bid + 1) & 1) * 512;
        i4 c0 = poll16(gbase + 2 * u, bid + 1);
        i4 c1 = poll16(gbase + 2 * u + 1, bid + 1);
        G4.x = i2f(c0.x); G4.y = i2f(c0.y); G4.z = i2f(c1.x); G4.w = i2f(c1.y);
      }
    }
  }

  // ---- epilogue: z_256
  pollf(fChr, 256, tid, sX);
  __syncthreads();
  if (wave < 4) {
    float dM = 0.f;
#pragma unroll
    for (int q = 0; q < 4; ++q) {
      float4 xf = *(const float4*)(sX + 4 * lane + 256 * q);
      dM = fmaf(rMo[q].x, xf.x, dM); dM = fmaf(rMo[q].y, xf.y, dM);
      dM = fmaf(rMo[q].z, xf.z, dM); dM = fmaf(rMo[q].w, xf.w, dM);
    }
    dM = wred(dM);
    if (lane == 0) astore(Z + (size_t)256 * 1024 + r, z_prev + dM + mob_own);
  }
}

extern "C" void kernel_launch(void* const* d_in, const int* in_sizes, int n_in,
                              void* d_out, int out_size, void* d_ws, size_t ws_size,
                              hipStream_t stream) {
  (void)in_sizes; (void)n_in; (void)out_size; (void)ws_size;
  hipMemsetAsync(d_ws, 0, 577536, stream);  // bar + all chunk tag regions
  tcell<<<dim3(NBLK), dim3(NTHR), 0, stream>>>(
      (const float*)d_in[0],  (const float*)d_in[1],
      (const float*)d_in[2],  (const float*)d_in[3],  (const float*)d_in[4],
      (const float*)d_in[5],  (const float*)d_in[6],
      (const float*)d_in[7],  (const float*)d_in[8],
      (const float*)d_in[9],  (const float*)d_in[10],
      (const float*)d_in[11], (const float*)d_in[12],
      (const float*)d_in[13], (const float*)d_in[14],
      (const float*)d_in[15], (const float*)d_in[16],
      (const float*)d_in[17], (const float*)d_in[18],
      (const float*)d_in[19], (const float*)d_in[20],
      (float*)d_out, (float*)d_ws);
}

// Round 15
// 3189.236 us; speedup vs baseline: 1.1033x; 1.1033x over previous
//
#include <hip/hip_runtime.h>
#include <math.h>

// TransformerCell — 4-hop dataflow (R13 layout) + 2-ROW-WAVE DIRECT FIRE.
// Chunks stay 512 x {2 values, pad, tag} x8 replicas (R14's 1-val chunks
// doubled LLC traffic and regressed). Waves 0-1 each compute BOTH rows of one
// chunk; after wred2 every lane holds both values -> lanes 0-7 fire the 8
// replicas directly. No producer __syncthreads / LDS round trip in SM/C/D.
// Staging double-buffered (sXa: A'/D, sXb: C/GWORK) so the removed barriers
// cannot create write-after-read races (each pair separated by an existing
// full-block barrier; explicit sync at loop end for t>=255 where GWORK's
// barrier is absent). Everything else identical to R13.

#define NTHR 512
#define NBLK 256

#define B_AC   4096     /* aC  [8][256] chunks */
#define B_SM   36864    /* smC [8][512] */
#define B_C    102400   /* cCh [8][512] */
#define B_F    167936   /* fCh [8][512] (f3) */
#define B_ZM   233472   /* zmC [8][512] (prologue) */
#define B_GC   299008   /* gC [2 parity][512] chunks */
#define B_DV   315392   /* dVec float[2][1024] */

typedef int i4 __attribute__((ext_vector_type(4)));

__device__ __forceinline__ float i2f(int x) { return __int_as_float(x); }
__device__ __forceinline__ int f2i(float x) { return __float_as_int(x); }

__device__ __forceinline__ void astore(float* p, float v) {
  __hip_atomic_store(p, v, __ATOMIC_RELAXED, __HIP_MEMORY_SCOPE_AGENT);
}
__device__ __forceinline__ float2 aload2(const float* p) {
  double d = __hip_atomic_load((double*)p, __ATOMIC_RELAXED, __HIP_MEMORY_SCOPE_AGENT);
  return __builtin_bit_cast(float2, d);
}
__device__ __forceinline__ int aloadI(const int* p) {
  return __hip_atomic_load((int*)p, __ATOMIC_RELAXED, __HIP_MEMORY_SCOPE_AGENT);
}
__device__ __forceinline__ int afaddI(int* p) {
  return __hip_atomic_fetch_add(p, 1, __ATOMIC_RELAXED, __HIP_MEMORY_SCOPE_AGENT);
}

__device__ __forceinline__ i4 poll16(const i4* p, int tag) {
  i4 v;
  for (;;) {
    asm volatile("global_load_dwordx4 %0, %1, off sc0 sc1\n\ts_waitcnt vmcnt(0)"
                 : "=&v"(v) : "v"(p) : "memory");
    if (v.w == tag) return v;
    __builtin_amdgcn_s_sleep(1);
  }
}
__device__ __forceinline__ void store16(i4* p, i4 v) {
  asm volatile("global_store_dwordx4 %0, %1, off sc0 sc1" :: "v"(p), "v"(v) : "memory");
}

__device__ __forceinline__ float wred(float v) {
#pragma unroll
  for (int o = 1; o < 64; o <<= 1) v += __shfl_xor(v, o, 64);
  return v;
}
__device__ __forceinline__ void wred2(float& a, float& b) {
#pragma unroll
  for (int o = 1; o < 64; o <<= 1) { a += __shfl_xor(a, o, 64); b += __shfl_xor(b, o, 64); }
}
__device__ __forceinline__ void wred3(float& a, float& b, float& c) {
#pragma unroll
  for (int o = 1; o < 64; o <<= 1) {
    a += __shfl_xor(a, o, 64); b += __shfl_xor(b, o, 64); c += __shfl_xor(c, o, 64);
  }
}
__device__ __forceinline__ float wmax(float v) {
#pragma unroll
  for (int o = 1; o < 64; o <<= 1) v = fmaxf(v, __shfl_xor(v, o, 64));
  return v;
}
__device__ __forceinline__ float lrelu(float x) { return x > 0.f ? x : 0.01f * x; }

__device__ __forceinline__ void gsync1(int* bar, int bid, int tid, int lane) {
  asm volatile("" ::: "memory");
  __builtin_amdgcn_s_waitcnt(0);
  __syncthreads();
  if (tid == 0) afaddI(bar + (bid & 7) * 16);
  if (tid < 64) {
    for (;;) {
      int v = (lane < 8) ? aloadI(bar + lane * 16) : 0x7fffffff;
      if (__all(v >= 32)) break;
      __builtin_amdgcn_s_sleep(2);
    }
  }
  __syncthreads();
  asm volatile("" ::: "memory");
}

__global__ void __launch_bounds__(NTHR) tcell(
    const float* __restrict__ mu, const float* __restrict__ z0,
    const float* __restrict__ W1, const float* __restrict__ W2, const float* __restrict__ W3,
    const float* __restrict__ p_in_w, const float* __restrict__ p_in_b,
    const float* __restrict__ p_h0_w, const float* __restrict__ p_h0_b,
    const float* __restrict__ p_h1_w, const float* __restrict__ p_h1_b,
    const float* __restrict__ p_out_w, const float* __restrict__ p_out_b,
    const float* __restrict__ m_in_w, const float* __restrict__ m_in_b,
    const float* __restrict__ m_h0_w, const float* __restrict__ m_h0_b,
    const float* __restrict__ m_h1_w, const float* __restrict__ m_h1_b,
    const float* __restrict__ m_out_w, const float* __restrict__ m_out_b,
    float* __restrict__ Z, float* __restrict__ ws) {
  const int tid = threadIdx.x;
  const int bid = blockIdx.x;
  const int lane = tid & 63;
  const int wave = tid >> 6;            // 0..7
  const int r = 4 * bid + (wave & 3);
  const int rep = bid & 7;

  char* wsb = (char*)ws;
  int* bar = (int*)wsb;
  i4* aC  = (i4*)(wsb + B_AC);
  i4* smC = (i4*)(wsb + B_SM);
  i4* cCh = (i4*)(wsb + B_C);
  i4* fCh = (i4*)(wsb + B_F);
  i4* zmC = (i4*)(wsb + B_ZM);
  i4* gC  = (i4*)(wsb + B_GC);
  float* dVec = (float*)(wsb + B_DV);
  i4* aCr  = aC  + rep * 256;
  i4* smCr = smC + rep * 512;
  i4* cChr = cCh + rep * 512;
  i4* fChr = fCh + rep * 512;
  i4* zmCr = zmC + rep * 512;

  __shared__ float sXa[1024], sXb[1024], sDv[1024];
  __shared__ float sLg[256], sNp[256], sPp[256], sR[256];
  __shared__ float sBigB[4][1024], sBigW[4][1024];
  __shared__ float sU[4][257];
  __shared__ float shD[4], shDp[4], shZ[4], shG[4], shGv[4];

  // ---- P0: waves 0-3 build B=W1@W2, W~=m_in_w@W3 rows (regs); wave 4: p_in
  float4 rB4[4], rW4[4];
  if (wave < 4) {
#pragma unroll
    for (int q = 0; q < 4; ++q) {
      rB4[q] = make_float4(0.f, 0.f, 0.f, 0.f);
      rW4[q] = make_float4(0.f, 0.f, 0.f, 0.f);
    }
    const float* __restrict__ w1r = W1 + (size_t)r * 512;
    const float* __restrict__ mir = m_in_w + (size_t)r * 512;
    for (int k = 0; k < 512; k += 2) {
      float w1a = w1r[k], w1b = w1r[k + 1];
      float mia = mir[k], mib = mir[k + 1];
      const float* w2a = W2 + (size_t)k * 1024 + 4 * lane;
      const float* w3a = W3 + (size_t)k * 1024 + 4 * lane;
#pragma unroll
      for (int q = 0; q < 4; ++q) {
        float4 a0 = *(const float4*)(w2a + 256 * q);
        float4 a1 = *(const float4*)(w2a + 1024 + 256 * q);
        float4 b0 = *(const float4*)(w3a + 256 * q);
        float4 b1 = *(const float4*)(w3a + 1024 + 256 * q);
        rB4[q].x = fmaf(w1a, a0.x, fmaf(w1b, a1.x, rB4[q].x));
        rB4[q].y = fmaf(w1a, a0.y, fmaf(w1b, a1.y, rB4[q].y));
        rB4[q].z = fmaf(w1a, a0.z, fmaf(w1b, a1.z, rB4[q].z));
        rB4[q].w = fmaf(w1a, a0.w, fmaf(w1b, a1.w, rB4[q].w));
        rW4[q].x = fmaf(mia, b0.x, fmaf(mib, b1.x, rW4[q].x));
        rW4[q].y = fmaf(mia, b0.y, fmaf(mib, b1.y, rW4[q].y));
        rW4[q].z = fmaf(mia, b0.z, fmaf(mib, b1.z, rW4[q].z));
        rW4[q].w = fmaf(mia, b0.w, fmaf(mib, b1.w, rW4[q].w));
      }
    }
  } else if (wave == 4) {
    float f[4];
#pragma unroll
    for (int j = 0; j < 4; ++j) {
      int row = 4 * bid + j;
      float acc = p_in_w[(size_t)row * 64 + lane] * mu[lane];
      acc = wred(acc);
      f[j] = lrelu(acc + p_in_b[row]);
    }
    if (lane < 16) {
      int rp = lane >> 1, ch = lane & 1;
      i4 c; c.x = f2i(f[2 * ch]); c.y = f2i(f[2 * ch + 1]); c.z = 0; c.w = 1;
      store16(smC + rp * 512 + 2 * bid + ch, c);
    }
  }

// 2-row-wave MVP: stage into BUF, waves 0-1 compute 2 rows each, direct fire.
#define MVP(WPTR, BPTR, ACT, INC, INTAG, OUTC, OUTTAG, BUF)                    \
  { i4 v = poll16((INC) + tid, (INTAG));                                       \
    BUF[2*tid] = i2f(v.x); BUF[2*tid+1] = i2f(v.y); }                          \
  __syncthreads();                                                             \
  if (wave < 2) {                                                              \
    int ra = 4 * bid + 2 * wave, rb = ra + 1;                                  \
    const float* wa = (WPTR) + (size_t)ra * 1024 + 4 * lane;                   \
    const float* wb = (WPTR) + (size_t)rb * 1024 + 4 * lane;                   \
    float a0 = 0.f, a1 = 0.f;                                                  \
    _Pragma("unroll")                                                          \
    for (int q = 0; q < 4; ++q) {                                              \
      float4 xf = *(const float4*)(BUF + 4 * lane + 256 * q);                  \
      float4 w0 = *(const float4*)(wa + 256 * q);                              \
      float4 w1 = *(const float4*)(wb + 256 * q);                              \
      a0 = fmaf(w0.x, xf.x, a0); a0 = fmaf(w0.y, xf.y, a0);                    \
      a0 = fmaf(w0.z, xf.z, a0); a0 = fmaf(w0.w, xf.w, a0);                    \
      a1 = fmaf(w1.x, xf.x, a1); a1 = fmaf(w1.y, xf.y, a1);                    \
      a1 = fmaf(w1.z, xf.z, a1); a1 = fmaf(w1.w, xf.w, a1);                    \
    }                                                                          \
    wred2(a0, a1);                                                             \
    float v0 = a0 + (BPTR)[ra], v1 = a1 + (BPTR)[rb];                          \
    if (ACT) { v0 = lrelu(v0); v1 = lrelu(v1); }                               \
    if (lane < 8) {                                                            \
      i4 c; c.x = f2i(v0); c.y = f2i(v1); c.z = 0; c.w = (OUTTAG);             \
      store16((OUTC) + lane * 512 + 2 * bid + wave, c);                        \
    }                                                                          \
  }

  // ---- P1..P2 (MLP_p chain)
  MVP(p_h0_w, p_h0_b, 1, smCr, 1, cCh, 1, sXb)
  MVP(p_h1_w, p_h1_b, 1, cChr, 1, fCh, 1, sXa)
  // ---- P3: z_minus -> zmC + Z[0]; Z[1] = z0
  { i4 v = poll16(fChr + tid, 1); sXb[2*tid] = i2f(v.x); sXb[2*tid+1] = i2f(v.y); }
  __syncthreads();
  if (wave < 2) {
    int ra = 4 * bid + 2 * wave, rb = ra + 1;
    const float* wa = p_out_w + (size_t)ra * 1024 + 4 * lane;
    const float* wb = p_out_w + (size_t)rb * 1024 + 4 * lane;
    float a0 = 0.f, a1 = 0.f;
#pragma unroll
    for (int q = 0; q < 4; ++q) {
      float4 xf = *(const float4*)(sXb + 4 * lane + 256 * q);
      float4 w0 = *(const float4*)(wa + 256 * q);
      float4 w1 = *(const float4*)(wb + 256 * q);
      a0 = fmaf(w0.x, xf.x, a0); a0 = fmaf(w0.y, xf.y, a0);
      a0 = fmaf(w0.z, xf.z, a0); a0 = fmaf(w0.w, xf.w, a0);
      a1 = fmaf(w1.x, xf.x, a1); a1 = fmaf(w1.y, xf.y, a1);
      a1 = fmaf(w1.z, xf.z, a1); a1 = fmaf(w1.w, xf.w, a1);
    }
    wred2(a0, a1);
    float v0 = a0 + p_out_b[ra], v1 = a1 + p_out_b[rb];
    if (lane < 8) {
      i4 c; c.x = f2i(v0); c.y = f2i(v1); c.z = 0; c.w = 1;
      store16(zmC + lane * 512 + 2 * bid + wave, c);
    }
    if (lane == 8) { astore(Z + ra, v0); astore(Z + rb, v1); }
  }
  if (bid < 2) Z[1024 + bid * 512 + tid] = z0[bid * 512 + tid];

  // ---- P4: z_minus -> sDv; z0 -> sXa; append rows 0 and 1
  float d0_w = 0.f, d_prev = 0.f, z_prev = 0.f;
  { i4 v = poll16(zmCr + tid, 1); sDv[2*tid] = i2f(v.x); sDv[2*tid+1] = i2f(v.y); }
  { float2 a = *(const float2*)(z0 + 2 * tid); sXa[2*tid] = a.x; sXa[2*tid+1] = a.y; }
  __syncthreads();
  if (wave < 4) {
    float aD = 0.f, aU = 0.f, bD = 0.f, bU = 0.f;
#pragma unroll
    for (int q = 0; q < 4; ++q) {
      float4 zm = *(const float4*)(sDv + 4 * lane + 256 * q);
      float4 z1 = *(const float4*)(sXa + 4 * lane + 256 * q);
      aD = fmaf(rB4[q].x, zm.x, aD); aD = fmaf(rB4[q].y, zm.y, aD);
      aD = fmaf(rB4[q].z, zm.z, aD); aD = fmaf(rB4[q].w, zm.w, aD);
      aU = fmaf(rW4[q].x, zm.x, aU); aU = fmaf(rW4[q].y, zm.y, aU);
      aU = fmaf(rW4[q].z, zm.z, aU); aU = fmaf(rW4[q].w, zm.w, aU);
      bD = fmaf(rB4[q].x, z1.x, bD); bD = fmaf(rB4[q].y, z1.y, bD);
      bD = fmaf(rB4[q].z, z1.z, bD); bD = fmaf(rB4[q].w, z1.w, bD);
      bU = fmaf(rW4[q].x, z1.x, bU); bU = fmaf(rW4[q].y, z1.y, bU);
      bU = fmaf(rW4[q].z, z1.z, bU); bU = fmaf(rW4[q].w, z1.w, bU);
    }
    wred2(aD, aU); wred2(bD, bU);
    d0_w = aD; d_prev = bD; z_prev = z0[r];
    if (lane == 0) {
      sU[wave][0] = aU; sU[wave][1] = bU;
      astore(dVec + 1024 + r, aD);   // dVec[1] = d_0
      astore(dVec + r, bD);          // dVec[0] = d_1
    }
  }
  gsync1(bar, bid, tid, lane);

  // ---- rMT: own row of M^T (column r of m_out_w) — one-time strided read
  float4 rMT[4];
  if (wave < 4) {
#pragma unroll
    for (int q = 0; q < 4; ++q) {
      int m0 = 4 * lane + 256 * q;
      rMT[q].x = m_out_w[(size_t)(m0 + 0) * 1024 + r];
      rMT[q].y = m_out_w[(size_t)(m0 + 1) * 1024 + r];
      rMT[q].z = m_out_w[(size_t)(m0 + 2) * 1024 + r];
      rMT[q].w = m_out_w[(size_t)(m0 + 3) * 1024 + r];
    }
  }

  // per-block state
  float lgreg = 0.f, dmob = 0.f;
  float4 G4 = make_float4(0.f, 0.f, 0.f, 0.f);

#define GWORK(PAR, TAG, ROWID)                                                 \
  { float2 a = aload2(dVec + (PAR) * 1024 + 2 * tid);                          \
    sDv[2*tid] = a.x; sDv[2*tid+1] = a.y; }                                    \
  __syncthreads();                                                             \
  if (wave < 4) {                                                              \
    float acc = 0.f;                                                           \
    _Pragma("unroll")                                                          \
    for (int q = 0; q < 4; ++q) {                                              \
      float4 d4 = *(const float4*)(sDv + 4 * lane + 256 * q);                  \
      acc = fmaf(rMT[q].x, d4.x, acc); acc = fmaf(rMT[q].y, d4.y, acc);        \
      acc = fmaf(rMT[q].z, d4.z, acc); acc = fmaf(rMT[q].w, d4.w, acc);        \
    }                                                                          \
    acc = wred(acc);                                                           \
    if (lane == 0) shGv[wave] = acc;                                           \
  }                                                                            \
  { float pd = sDv[tid] * m_out_b[tid] + sDv[tid+512] * m_out_b[tid+512];      \
    sXb[tid] = pd; }                                                           \
  __syncthreads();                                                             \
  if (wave == 0) {                                                             \
    float s = sXb[lane] + sXb[lane+64] + sXb[lane+128] + sXb[lane+192]         \
            + sXb[lane+256] + sXb[lane+320] + sXb[lane+384] + sXb[lane+448];   \
    s = wred(s);                                                               \
    if (bid == (ROWID)) dmob = s;                                              \
    if (lane < 2) {                                                            \
      i4 c; c.x = f2i(shGv[2*lane]); c.y = f2i(shGv[2*lane+1]); c.z = 0;       \
      c.w = (TAG);                                                             \
      store16(gC + (PAR) * 512 + 2 * bid + lane, c);                           \
    }                                                                          \
  }

  // G-work for row 0 (appended in prologue)
  GWORK(1, 1, 0)

  // ---- precompute rBM=(B@M) row, rWM=(W~@M) row, rMo=M row, biases
  float4 rBM[4], rWM[4], rMo[4];
  float bmob = 0.f, wmob = 0.f, mob_own = 0.f;
  if (wave < 4) {
#pragma unroll
    for (int q = 0; q < 4; ++q) {
      *(float4*)(&sBigB[wave][4 * lane + 256 * q]) = rB4[q];
      *(float4*)(&sBigW[wave][4 * lane + 256 * q]) = rW4[q];
      rBM[q] = make_float4(0.f, 0.f, 0.f, 0.f);
      rWM[q] = make_float4(0.f, 0.f, 0.f, 0.f);
    }
  }
  __syncthreads();
  if (wave < 4) {
    for (int m = 0; m < 1024; ++m) {
      float bB = sBigB[wave][m], bW = sBigW[wave][m];
      float mb = m_out_b[m];
      bmob = fmaf(bB, mb, bmob); wmob = fmaf(bW, mb, wmob);
      const float* mo = m_out_w + (size_t)m * 1024 + 4 * lane;
#pragma unroll
      for (int q = 0; q < 4; ++q) {
        float4 m4 = *(const float4*)(mo + 256 * q);
        rBM[q].x = fmaf(bB, m4.x, rBM[q].x); rBM[q].y = fmaf(bB, m4.y, rBM[q].y);
        rBM[q].z = fmaf(bB, m4.z, rBM[q].z); rBM[q].w = fmaf(bB, m4.w, rBM[q].w);
        rWM[q].x = fmaf(bW, m4.x, rWM[q].x); rWM[q].y = fmaf(bW, m4.y, rWM[q].y);
        rWM[q].z = fmaf(bW, m4.z, rWM[q].z); rWM[q].w = fmaf(bW, m4.w, rWM[q].w);
      }
    }
#pragma unroll
    for (int q = 0; q < 4; ++q)
      rMo[q] = *(const float4*)(m_out_w + (size_t)r * 1024 + 4 * lane + 256 * q);
    mob_own = m_out_b[r];
  }

  // ---- main recurrence: A' -> SM -> C -> D (+offpath G)
  for (int t = 2; t <= 256; ++t) {
    // ---------- Phase A' ----------
    if (t == 2) {
      if (wave < 4 && lane == 0) { shD[wave] = d_prev; shDp[wave] = d0_w; shZ[wave] = z_prev; }
      __syncthreads();
    } else {
      { i4 v = poll16(fChr + tid, t - 1); sXa[2*tid] = i2f(v.x); sXa[2*tid+1] = i2f(v.y); }
      __syncthreads();
      if (wave < 4) {
        float dB = 0.f, dW = 0.f, dM = 0.f;
#pragma unroll
        for (int q = 0; q < 4; ++q) {
          float4 xf = *(const float4*)(sXa + 4 * lane + 256 * q);
          dB = fmaf(rBM[q].x, xf.x, dB); dB = fmaf(rBM[q].y, xf.y, dB);
          dB = fmaf(rBM[q].z, xf.z, dB); dB = fmaf(rBM[q].w, xf.w, dB);
          dW = fmaf(rWM[q].x, xf.x, dW); dW = fmaf(rWM[q].y, xf.y, dW);
          dW = fmaf(rWM[q].z, xf.z, dW); dW = fmaf(rWM[q].w, xf.w, dW);
          dM = fmaf(rMo[q].x, xf.x, dM); dM = fmaf(rMo[q].y, xf.y, dM);
          dM = fmaf(rMo[q].z, xf.z, dM); dM = fmaf(rMo[q].w, xf.w, dM);
        }
        wred3(dB, dW, dM);
        float d_new = d_prev + dB + bmob;
        float U_new = sU[wave][t - 2] + dW + wmob;
        float z_new = z_prev + dM + mob_own;
        if (lane == 0) {
          sU[wave][t - 1] = U_new;
          astore(Z + (size_t)(t - 1) * 1024 + r, z_new);
          astore(dVec + (t & 1) * 1024 + r, d_new);
          shD[wave] = d_new; shDp[wave] = d_prev; shZ[wave] = z_new;
        }
        __builtin_amdgcn_s_waitcnt(0);   // drain d/Z stores before aC evidences them
        d_prev = d_new; z_prev = z_new;
      } else {
        int u = tid - 256;
        float gp = G4.x * sXa[4*u] + G4.y * sXa[4*u+1] + G4.z * sXa[4*u+2] + G4.w * sXa[4*u+3];
        gp = wred(gp);
        if (lane == 0) shG[wave - 4] = gp;
      }
      __syncthreads();
    }
    if (wave == 0) {
      float np = shD[0]*shZ[0] + shD[1]*shZ[1] + shD[2]*shZ[2] + shD[3]*shZ[3];
      float pp = shDp[0]*shZ[0] + shDp[1]*shZ[1] + shDp[2]*shZ[2] + shDp[3]*shZ[3];
      if (t >= 3 && bid <= t - 3)
        lgreg += shG[0] + shG[1] + shG[2] + shG[3] + dmob;
      if (lane < 8) {
        i4 c; c.x = f2i(lgreg); c.y = f2i(np); c.z = f2i(pp); c.w = t;
        store16(aC + lane * 256 + bid, c);
      }
    }

    // ---------- Phase SM ----------
    if (tid < 256) {
      i4 v = poll16(aCr + tid, t);
      sLg[tid] = i2f(v.x); sNp[tid] = i2f(v.y); sPp[tid] = i2f(v.z);
    }
    __syncthreads();
    if (wave == 0) {
      float ns = sNp[lane] + sNp[lane+64] + sNp[lane+128] + sNp[lane+192];
      float ps = sPp[lane] + sPp[lane+64] + sPp[lane+128] + sPp[lane+192];
      wred2(ns, ps);
      if (bid == t - 2) lgreg = ps;      // capture (unscaled)
      float l[4]; float mx = -1e30f;
#pragma unroll
      for (int j = 0; j < 4; ++j) {
        int i = lane + 64 * j;
        float li = -1e30f;
        if (i <= t - 3) li = sLg[i] * 0.03125f;
        else if (i == t - 2) li = ps * 0.03125f;
        else if (i == t - 1) li = ns * 0.03125f;
        l[j] = li; mx = fmaxf(mx, li);
      }
      mx = wmax(mx);
      float m = fmaxf(mx, 0.f);
      float e[4], es = 0.f;
#pragma unroll
      for (int j = 0; j < 4; ++j) {
        int i = lane + 64 * j;
        e[j] = (i <= t - 1) ? __expf(l[j] - m) : 0.f;
        es += e[j];
      }
      es = wred(es);
      float inv = 1.f / (es + (float)(257 - t) * __expf(-m));
#pragma unroll
      for (int j = 0; j < 4; ++j) sR[lane + 64 * j] = e[j] * inv;
    }
    __syncthreads();
    if (wave < 2) {                       // f1: 2 rows/wave, direct fire
      int ra = 4 * bid + 2 * wave;
      float a0 = 0.f, a1 = 0.f;
#pragma unroll
      for (int j = 0; j < 4; ++j) {
        int i = lane + 64 * j;
        if (i <= t - 1) {
          float av = sR[i];
          a0 = fmaf(av, sU[2 * wave][i], a0);
          a1 = fmaf(av, sU[2 * wave + 1][i], a1);
        }
      }
      wred2(a0, a1);
      float v0 = lrelu(a0 + m_in_b[ra]);
      float v1 = lrelu(a1 + m_in_b[ra + 1]);
      if (lane < 8) {
        i4 c; c.x = f2i(v0); c.y = f2i(v1); c.z = 0; c.w = t;
        store16(smC + lane * 512 + 2 * bid + wave, c);
      }
    }

    // ---------- Phase C ----------
    MVP(m_h0_w, m_h0_b, 1, smCr, t, cCh, t, sXb)

    // ---------- Phase D (fires f3) ----------
    MVP(m_h1_w, m_h1_b, 1, cChr, t, fCh, t, sXa)

    // ---------- off-path: G work for row t-1 ----------
    if (t <= 254) {
      GWORK((t & 1), t, t - 1)
    } else {
      __syncthreads();   // protect D-compute read of sXa vs next stage (no GWORK barrier)
    }
    // ---------- off-path: collect own G (row=bid, fired at step bid+1) ----------
    if (t == bid + 2 && bid <= 253) {
      if (tid >= 256) {
        int u = tid - 256;
        const i4* gbase = gC + ((bid + 1) & 1) * 512;
        i4 c0 = poll16(gbase + 2 * u, bid + 1);
        i4 c1 = poll16(gbase + 2 * u + 1, bid + 1);
        G4.x = i2f(c0.x); G4.y = i2f(c0.y); G4.z = i2f(c1.x); G4.w = i2f(c1.y);
      }
    }
  }

  // ---- epilogue: z_256
  { i4 v = poll16(fChr + tid, 256); sXa[2*tid] = i2f(v.x); sXa[2*tid+1] = i2f(v.y); }
  __syncthreads();
  if (wave < 4) {
    float dM = 0.f;
#pragma unroll
    for (int q = 0; q < 4; ++q) {
      float4 xf = *(const float4*)(sXa + 4 * lane + 256 * q);
      dM = fmaf(rMo[q].x, xf.x, dM); dM = fmaf(rMo[q].y, xf.y, dM);
      dM = fmaf(rMo[q].z, xf.z, dM); dM = fmaf(rMo[q].w, xf.w, dM);
    }
    dM = wred(dM);
    if (lane == 0) astore(Z + (size_t)256 * 1024 + r, z_prev + dM + mob_own);
  }
}

extern "C" void kernel_launch(void* const* d_in, const int* in_sizes, int n_in,
                              void* d_out, int out_size, void* d_ws, size_t ws_size,
                              hipStream_t stream) {
  (void)in_sizes; (void)n_in; (void)out_size; (void)ws_size;
  hipMemsetAsync(d_ws, 0, 315392, stream);  // bar + all chunk tag regions
  tcell<<<dim3(NBLK), dim3(NTHR), 0, stream>>>(
      (const float*)d_in[0],  (const float*)d_in[1],
      (const float*)d_in[2],  (const float*)d_in[3],  (const float*)d_in[4],
      (const float*)d_in[5],  (const float*)d_in[6],
      (const float*)d_in[7],  (const float*)d_in[8],
      (const float*)d_in[9],  (const float*)d_in[10],
      (const float*)d_in[11], (const float*)d_in[12],
      (const float*)d_in[13], (const float*)d_in[14],
      (const float*)d_in[15], (const float*)d_in[16],
      (const float*)d_in[17], (const float*)d_in[18],
      (const float*)d_in[19], (const float*)d_in[20],
      (float*)d_out, (float*)d_ws);
}

// Round 16
// 2863.092 us; speedup vs baseline: 1.2290x; 1.1139x over previous
//
#include <hip/hip_runtime.h>
#include <math.h>

// TransformerCell — FINAL: 4-hop fused data+tag dataflow (R13, verified best).
// A'(f3 -> d,U,z via linear recurrences; logits) -> SM -> C -> D; 255 steps.
//   d_{t-1} = d_{t-2} + (B@M)f3 + B·b ; U, z likewise (per-wave rows of
//   B=W1@W2, W~=m_in_w@W3, B@M, W~@M, M precomputed into registers).
// Old-row logits: per-block recurrence lg_i += (M^T d_i)·f3 + d_i·b with
// G_i = M^T d_i from register-resident M^T rows (rMT), routed via parity gC
// chunks (2-step slack, hidden in hop latency). Rows t-1/t-2 via partials in aC.
// All exchanges: 16B {2 payloads, pad, tag} chunks x8 replicas, sc0 sc1
// stores, per-thread polling. Tags memset each launch (replay-deterministic).
// R14 (1-val chunks) and R15 (2-row waves) both regressed — this is the
// balanced configuration.

#define NTHR 512
#define NBLK 256

#define B_AC   4096     /* aC  [8][256] chunks */
#define B_SM   36864    /* smC [8][512] */
#define B_C    102400   /* cCh [8][512] */
#define B_F    167936   /* fCh [8][512] (f3) */
#define B_ZM   233472   /* zmC [8][512] (prologue) */
#define B_GC   299008   /* gC [2 parity][512] chunks */
#define B_DV   315392   /* dVec float[2][1024] */

typedef int i4 __attribute__((ext_vector_type(4)));

__device__ __forceinline__ float i2f(int x) { return __int_as_float(x); }
__device__ __forceinline__ int f2i(float x) { return __float_as_int(x); }

__device__ __forceinline__ void astore(float* p, float v) {
  __hip_atomic_store(p, v, __ATOMIC_RELAXED, __HIP_MEMORY_SCOPE_AGENT);
}
__device__ __forceinline__ float2 aload2(const float* p) {
  double d = __hip_atomic_load((double*)p, __ATOMIC_RELAXED, __HIP_MEMORY_SCOPE_AGENT);
  return __builtin_bit_cast(float2, d);
}
__device__ __forceinline__ int aloadI(const int* p) {
  return __hip_atomic_load((int*)p, __ATOMIC_RELAXED, __HIP_MEMORY_SCOPE_AGENT);
}
__device__ __forceinline__ int afaddI(int* p) {
  return __hip_atomic_fetch_add(p, 1, __ATOMIC_RELAXED, __HIP_MEMORY_SCOPE_AGENT);
}

__device__ __forceinline__ i4 poll16(const i4* p, int tag) {
  i4 v;
  for (;;) {
    asm volatile("global_load_dwordx4 %0, %1, off sc0 sc1\n\ts_waitcnt vmcnt(0)"
                 : "=&v"(v) : "v"(p) : "memory");
    if (v.w == tag) return v;
    __builtin_amdgcn_s_sleep(1);
  }
}
__device__ __forceinline__ void store16(i4* p, i4 v) {
  asm volatile("global_store_dwordx4 %0, %1, off sc0 sc1" :: "v"(p), "v"(v) : "memory");
}

__device__ __forceinline__ float wred(float v) {
#pragma unroll
  for (int o = 1; o < 64; o <<= 1) v += __shfl_xor(v, o, 64);
  return v;
}
__device__ __forceinline__ void wred2(float& a, float& b) {
#pragma unroll
  for (int o = 1; o < 64; o <<= 1) { a += __shfl_xor(a, o, 64); b += __shfl_xor(b, o, 64); }
}
__device__ __forceinline__ void wred3(float& a, float& b, float& c) {
#pragma unroll
  for (int o = 1; o < 64; o <<= 1) {
    a += __shfl_xor(a, o, 64); b += __shfl_xor(b, o, 64); c += __shfl_xor(c, o, 64);
  }
}
__device__ __forceinline__ float wmax(float v) {
#pragma unroll
  for (int o = 1; o < 64; o <<= 1) v = fmaxf(v, __shfl_xor(v, o, 64));
  return v;
}
__device__ __forceinline__ float lrelu(float x) { return x > 0.f ? x : 0.01f * x; }

__device__ __forceinline__ void gsync1(int* bar, int bid, int tid, int lane) {
  asm volatile("" ::: "memory");
  __builtin_amdgcn_s_waitcnt(0);
  __syncthreads();
  if (tid == 0) afaddI(bar + (bid & 7) * 16);
  if (tid < 64) {
    for (;;) {
      int v = (lane < 8) ? aloadI(bar + lane * 16) : 0x7fffffff;
      if (__all(v >= 32)) break;
      __builtin_amdgcn_s_sleep(2);
    }
  }
  __syncthreads();
  asm volatile("" ::: "memory");
}

__global__ void __launch_bounds__(NTHR) tcell(
    const float* __restrict__ mu, const float* __restrict__ z0,
    const float* __restrict__ W1, const float* __restrict__ W2, const float* __restrict__ W3,
    const float* __restrict__ p_in_w, const float* __restrict__ p_in_b,
    const float* __restrict__ p_h0_w, const float* __restrict__ p_h0_b,
    const float* __restrict__ p_h1_w, const float* __restrict__ p_h1_b,
    const float* __restrict__ p_out_w, const float* __restrict__ p_out_b,
    const float* __restrict__ m_in_w, const float* __restrict__ m_in_b,
    const float* __restrict__ m_h0_w, const float* __restrict__ m_h0_b,
    const float* __restrict__ m_h1_w, const float* __restrict__ m_h1_b,
    const float* __restrict__ m_out_w, const float* __restrict__ m_out_b,
    float* __restrict__ Z, float* __restrict__ ws) {
  const int tid = threadIdx.x;
  const int bid = blockIdx.x;
  const int lane = tid & 63;
  const int wave = tid >> 6;            // 0..7
  const int r = 4 * bid + (wave & 3);
  const int rep = bid & 7;

  char* wsb = (char*)ws;
  int* bar = (int*)wsb;
  i4* aC  = (i4*)(wsb + B_AC);
  i4* smC = (i4*)(wsb + B_SM);
  i4* cCh = (i4*)(wsb + B_C);
  i4* fCh = (i4*)(wsb + B_F);
  i4* zmC = (i4*)(wsb + B_ZM);
  i4* gC  = (i4*)(wsb + B_GC);
  float* dVec = (float*)(wsb + B_DV);
  i4* aCr  = aC  + rep * 256;
  i4* smCr = smC + rep * 512;
  i4* cChr = cCh + rep * 512;
  i4* fChr = fCh + rep * 512;
  i4* zmCr = zmC + rep * 512;

  __shared__ float sX[1024], sDv[1024];
  __shared__ float sLg[256], sNp[256], sPp[256], sR[256];
  __shared__ float sBigB[4][1024], sBigW[4][1024];
  __shared__ float sU[4][257];
  __shared__ float shD[4], shDp[4], shZ[4], shG[4], shGv[4], shF[4];

  // ---- P0: waves 0-3 build B=W1@W2, W~=m_in_w@W3 rows (regs); wave 4: p_in
  float4 rB4[4], rW4[4];
  if (wave < 4) {
#pragma unroll
    for (int q = 0; q < 4; ++q) {
      rB4[q] = make_float4(0.f, 0.f, 0.f, 0.f);
      rW4[q] = make_float4(0.f, 0.f, 0.f, 0.f);
    }
    const float* __restrict__ w1r = W1 + (size_t)r * 512;
    const float* __restrict__ mir = m_in_w + (size_t)r * 512;
    for (int k = 0; k < 512; k += 2) {
      float w1a = w1r[k], w1b = w1r[k + 1];
      float mia = mir[k], mib = mir[k + 1];
      const float* w2a = W2 + (size_t)k * 1024 + 4 * lane;
      const float* w3a = W3 + (size_t)k * 1024 + 4 * lane;
#pragma unroll
      for (int q = 0; q < 4; ++q) {
        float4 a0 = *(const float4*)(w2a + 256 * q);
        float4 a1 = *(const float4*)(w2a + 1024 + 256 * q);
        float4 b0 = *(const float4*)(w3a + 256 * q);
        float4 b1 = *(const float4*)(w3a + 1024 + 256 * q);
        rB4[q].x = fmaf(w1a, a0.x, fmaf(w1b, a1.x, rB4[q].x));
        rB4[q].y = fmaf(w1a, a0.y, fmaf(w1b, a1.y, rB4[q].y));
        rB4[q].z = fmaf(w1a, a0.z, fmaf(w1b, a1.z, rB4[q].z));
        rB4[q].w = fmaf(w1a, a0.w, fmaf(w1b, a1.w, rB4[q].w));
        rW4[q].x = fmaf(mia, b0.x, fmaf(mib, b1.x, rW4[q].x));
        rW4[q].y = fmaf(mia, b0.y, fmaf(mib, b1.y, rW4[q].y));
        rW4[q].z = fmaf(mia, b0.z, fmaf(mib, b1.z, rW4[q].z));
        rW4[q].w = fmaf(mia, b0.w, fmaf(mib, b1.w, rW4[q].w));
      }
    }
  } else if (wave == 4) {
    float f[4];
#pragma unroll
    for (int j = 0; j < 4; ++j) {
      int row = 4 * bid + j;
      float acc = p_in_w[(size_t)row * 64 + lane] * mu[lane];
      acc = wred(acc);
      f[j] = lrelu(acc + p_in_b[row]);
    }
    if (lane < 16) {
      int rp = lane >> 1, ch = lane & 1;
      i4 c; c.x = f2i(f[2 * ch]); c.y = f2i(f[2 * ch + 1]); c.z = 0; c.w = 1;
      store16(smC + rp * 512 + 2 * bid + ch, c);
    }
  }

#define MVP(WPTR, BPTR, ACT, INC, INTAG, OUTC, OUTTAG)                         \
  { i4 v = poll16((INC) + tid, (INTAG)); sX[2*tid] = i2f(v.x); sX[2*tid+1] = i2f(v.y); } \
  __syncthreads();                                                             \
  if (wave < 4) {                                                              \
    const float* w = (WPTR) + (size_t)r * 1024 + 4 * lane;                     \
    float acc = 0.f;                                                           \
    _Pragma("unroll")                                                          \
    for (int q = 0; q < 4; ++q) {                                              \
      float4 wf = *(const float4*)(w + 256 * q);                               \
      float4 xf = *(const float4*)(sX + 4 * lane + 256 * q);                   \
      acc = fmaf(wf.x, xf.x, acc); acc = fmaf(wf.y, xf.y, acc);                \
      acc = fmaf(wf.z, xf.z, acc); acc = fmaf(wf.w, xf.w, acc);                \
    }                                                                          \
    acc = wred(acc);                                                           \
    if (lane == 0) { float vv = acc + (BPTR)[r]; shF[wave] = (ACT) ? lrelu(vv) : vv; } \
  }                                                                            \
  __syncthreads();                                                             \
  if (tid < 16) {                                                              \
    int rp = tid >> 1, ch = tid & 1;                                           \
    i4 c; c.x = f2i(shF[2*ch]); c.y = f2i(shF[2*ch+1]); c.z = 0; c.w = (OUTTAG); \
    store16((OUTC) + rp * 512 + 2 * bid + ch, c);                              \
  }

  // ---- P1..P3 (MLP_p chain)
  MVP(p_h0_w, p_h0_b, 1, smCr, 1, cCh, 1)
  MVP(p_h1_w, p_h1_b, 1, cChr, 1, fCh, 1)
  MVP(p_out_w, p_out_b, 0, fChr, 1, zmC, 1)
  if (tid == 16) *(float4*)(Z + 4 * bid) = make_float4(shF[0], shF[1], shF[2], shF[3]);
  if (bid < 2) Z[1024 + bid * 512 + tid] = z0[bid * 512 + tid];

  // ---- P4: z_minus -> sDv; z0 -> sX; append rows 0 and 1
  float d0_w = 0.f, d_prev = 0.f, z_prev = 0.f;
  { i4 v = poll16(zmCr + tid, 1); sDv[2*tid] = i2f(v.x); sDv[2*tid+1] = i2f(v.y); }
  { float2 a = *(const float2*)(z0 + 2 * tid); sX[2*tid] = a.x; sX[2*tid+1] = a.y; }
  __syncthreads();
  if (wave < 4) {
    float aD = 0.f, aU = 0.f, bD = 0.f, bU = 0.f;
#pragma unroll
    for (int q = 0; q < 4; ++q) {
      float4 zm = *(const float4*)(sDv + 4 * lane + 256 * q);
      float4 z1 = *(const float4*)(sX + 4 * lane + 256 * q);
      aD = fmaf(rB4[q].x, zm.x, aD); aD = fmaf(rB4[q].y, zm.y, aD);
      aD = fmaf(rB4[q].z, zm.z, aD); aD = fmaf(rB4[q].w, zm.w, aD);
      aU = fmaf(rW4[q].x, zm.x, aU); aU = fmaf(rW4[q].y, zm.y, aU);
      aU = fmaf(rW4[q].z, zm.z, aU); aU = fmaf(rW4[q].w, zm.w, aU);
      bD = fmaf(rB4[q].x, z1.x, bD); bD = fmaf(rB4[q].y, z1.y, bD);
      bD = fmaf(rB4[q].z, z1.z, bD); bD = fmaf(rB4[q].w, z1.w, bD);
      bU = fmaf(rW4[q].x, z1.x, bU); bU = fmaf(rW4[q].y, z1.y, bU);
      bU = fmaf(rW4[q].z, z1.z, bU); bU = fmaf(rW4[q].w, z1.w, bU);
    }
    wred2(aD, aU); wred2(bD, bU);
    d0_w = aD; d_prev = bD; z_prev = z0[r];
    if (lane == 0) {
      sU[wave][0] = aU; sU[wave][1] = bU;
      astore(dVec + 1024 + r, aD);   // dVec[1] = d_0
      astore(dVec + r, bD);          // dVec[0] = d_1
    }
  }
  gsync1(bar, bid, tid, lane);

  // ---- rMT: own row of M^T (column r of m_out_w) — one-time strided read
  float4 rMT[4];
  if (wave < 4) {
#pragma unroll
    for (int q = 0; q < 4; ++q) {
      int m0 = 4 * lane + 256 * q;
      rMT[q].x = m_out_w[(size_t)(m0 + 0) * 1024 + r];
      rMT[q].y = m_out_w[(size_t)(m0 + 1) * 1024 + r];
      rMT[q].z = m_out_w[(size_t)(m0 + 2) * 1024 + r];
      rMT[q].w = m_out_w[(size_t)(m0 + 3) * 1024 + r];
    }
  }

  // per-block state
  float lgreg = 0.f, dmob = 0.f;
  float4 G4 = make_float4(0.f, 0.f, 0.f, 0.f);

#define GWORK(PAR, TAG, ROWID)                                                 \
  { float2 a = aload2(dVec + (PAR) * 1024 + 2 * tid);                          \
    sDv[2*tid] = a.x; sDv[2*tid+1] = a.y; }                                    \
  __syncthreads();                                                             \
  if (wave < 4) {                                                              \
    float acc = 0.f;                                                           \
    _Pragma("unroll")                                                          \
    for (int q = 0; q < 4; ++q) {                                              \
      float4 d4 = *(const float4*)(sDv + 4 * lane + 256 * q);                  \
      acc = fmaf(rMT[q].x, d4.x, acc); acc = fmaf(rMT[q].y, d4.y, acc);        \
      acc = fmaf(rMT[q].z, d4.z, acc); acc = fmaf(rMT[q].w, d4.w, acc);        \
    }                                                                          \
    acc = wred(acc);                                                           \
    if (lane == 0) shGv[wave] = acc;                                           \
  }                                                                            \
  { float pd = sDv[tid] * m_out_b[tid] + sDv[tid+512] * m_out_b[tid+512];      \
    sX[tid] = pd; }                                                            \
  __syncthreads();                                                             \
  if (wave == 0) {                                                             \
    float s = sX[lane] + sX[lane+64] + sX[lane+128] + sX[lane+192]             \
            + sX[lane+256] + sX[lane+320] + sX[lane+384] + sX[lane+448];       \
    s = wred(s);                                                               \
    if (bid == (ROWID)) dmob = s;                                              \
    if (lane < 2) {                                                            \
      i4 c; c.x = f2i(shGv[2*lane]); c.y = f2i(shGv[2*lane+1]); c.z = 0;       \
      c.w = (TAG);                                                             \
      store16(gC + (PAR) * 512 + 2 * bid + lane, c);                           \
    }                                                                          \
  }

  // G-work for row 0 (appended in prologue)
  GWORK(1, 1, 0)

  // ---- precompute rBM=(B@M) row, rWM=(W~@M) row, rMo=M row, biases
  float4 rBM[4], rWM[4], rMo[4];
  float bmob = 0.f, wmob = 0.f, mob_own = 0.f;
  if (wave < 4) {
#pragma unroll
    for (int q = 0; q < 4; ++q) {
      *(float4*)(&sBigB[wave][4 * lane + 256 * q]) = rB4[q];
      *(float4*)(&sBigW[wave][4 * lane + 256 * q]) = rW4[q];
      rBM[q] = make_float4(0.f, 0.f, 0.f, 0.f);
      rWM[q] = make_float4(0.f, 0.f, 0.f, 0.f);
    }
  }
  __syncthreads();
  if (wave < 4) {
    for (int m = 0; m < 1024; ++m) {
      float bB = sBigB[wave][m], bW = sBigW[wave][m];
      float mb = m_out_b[m];
      bmob = fmaf(bB, mb, bmob); wmob = fmaf(bW, mb, wmob);
      const float* mo = m_out_w + (size_t)m * 1024 + 4 * lane;
#pragma unroll
      for (int q = 0; q < 4; ++q) {
        float4 m4 = *(const float4*)(mo + 256 * q);
        rBM[q].x = fmaf(bB, m4.x, rBM[q].x); rBM[q].y = fmaf(bB, m4.y, rBM[q].y);
        rBM[q].z = fmaf(bB, m4.z, rBM[q].z); rBM[q].w = fmaf(bB, m4.w, rBM[q].w);
        rWM[q].x = fmaf(bW, m4.x, rWM[q].x); rWM[q].y = fmaf(bW, m4.y, rWM[q].y);
        rWM[q].z = fmaf(bW, m4.z, rWM[q].z); rWM[q].w = fmaf(bW, m4.w, rWM[q].w);
      }
    }
#pragma unroll
    for (int q = 0; q < 4; ++q)
      rMo[q] = *(const float4*)(m_out_w + (size_t)r * 1024 + 4 * lane + 256 * q);
    mob_own = m_out_b[r];
  }

  // ---- main recurrence: A' -> SM -> C -> D (+offpath G)
  for (int t = 2; t <= 256; ++t) {
    // ---------- Phase A' ----------
    if (t == 2) {
      if (wave < 4 && lane == 0) { shD[wave] = d_prev; shDp[wave] = d0_w; shZ[wave] = z_prev; }
      __syncthreads();
    } else {
      { i4 v = poll16(fChr + tid, t - 1); sX[2*tid] = i2f(v.x); sX[2*tid+1] = i2f(v.y); }
      __syncthreads();
      if (wave < 4) {
        float dB = 0.f, dW = 0.f, dM = 0.f;
#pragma unroll
        for (int q = 0; q < 4; ++q) {
          float4 xf = *(const float4*)(sX + 4 * lane + 256 * q);
          dB = fmaf(rBM[q].x, xf.x, dB); dB = fmaf(rBM[q].y, xf.y, dB);
          dB = fmaf(rBM[q].z, xf.z, dB); dB = fmaf(rBM[q].w, xf.w, dB);
          dW = fmaf(rWM[q].x, xf.x, dW); dW = fmaf(rWM[q].y, xf.y, dW);
          dW = fmaf(rWM[q].z, xf.z, dW); dW = fmaf(rWM[q].w, xf.w, dW);
          dM = fmaf(rMo[q].x, xf.x, dM); dM = fmaf(rMo[q].y, xf.y, dM);
          dM = fmaf(rMo[q].z, xf.z, dM); dM = fmaf(rMo[q].w, xf.w, dM);
        }
        wred3(dB, dW, dM);
        float d_new = d_prev + dB + bmob;
        float U_new = sU[wave][t - 2] + dW + wmob;
        float z_new = z_prev + dM + mob_own;
        if (lane == 0) {
          sU[wave][t - 1] = U_new;
          astore(Z + (size_t)(t - 1) * 1024 + r, z_new);
          astore(dVec + (t & 1) * 1024 + r, d_new);
          shD[wave] = d_new; shDp[wave] = d_prev; shZ[wave] = z_new;
        }
        __builtin_amdgcn_s_waitcnt(0);   // drain d/Z stores before aC evidences them
        d_prev = d_new; z_prev = z_new;
      } else {
        int u = tid - 256;
        float gp = G4.x * sX[4*u] + G4.y * sX[4*u+1] + G4.z * sX[4*u+2] + G4.w * sX[4*u+3];
        gp = wred(gp);
        if (lane == 0) shG[wave - 4] = gp;
      }
      __syncthreads();
    }
    if (wave == 0) {
      float np = shD[0]*shZ[0] + shD[1]*shZ[1] + shD[2]*shZ[2] + shD[3]*shZ[3];
      float pp = shDp[0]*shZ[0] + shDp[1]*shZ[1] + shDp[2]*shZ[2] + shDp[3]*shZ[3];
      if (t >= 3 && bid <= t - 3)
        lgreg += shG[0] + shG[1] + shG[2] + shG[3] + dmob;
      if (lane < 8) {
        i4 c; c.x = f2i(lgreg); c.y = f2i(np); c.z = f2i(pp); c.w = t;
        store16(aC + lane * 256 + bid, c);
      }
    }

    // ---------- Phase SM ----------
    if (tid < 256) {
      i4 v = poll16(aCr + tid, t);
      sLg[tid] = i2f(v.x); sNp[tid] = i2f(v.y); sPp[tid] = i2f(v.z);
    }
    __syncthreads();
    if (wave == 0) {
      float ns = sNp[lane] + sNp[lane+64] + sNp[lane+128] + sNp[lane+192];
      float ps = sPp[lane] + sPp[lane+64] + sPp[lane+128] + sPp[lane+192];
      wred2(ns, ps);
      if (bid == t - 2) lgreg = ps;      // capture (unscaled)
      float l[4]; float mx = -1e30f;
#pragma unroll
      for (int j = 0; j < 4; ++j) {
        int i = lane + 64 * j;
        float li = -1e30f;
        if (i <= t - 3) li = sLg[i] * 0.03125f;
        else if (i == t - 2) li = ps * 0.03125f;
        else if (i == t - 1) li = ns * 0.03125f;
        l[j] = li; mx = fmaxf(mx, li);
      }
      mx = wmax(mx);
      float m = fmaxf(mx, 0.f);
      float e[4], es = 0.f;
#pragma unroll
      for (int j = 0; j < 4; ++j) {
        int i = lane + 64 * j;
        e[j] = (i <= t - 1) ? __expf(l[j] - m) : 0.f;
        es += e[j];
      }
      es = wred(es);
      float inv = 1.f / (es + (float)(257 - t) * __expf(-m));
#pragma unroll
      for (int j = 0; j < 4; ++j) sR[lane + 64 * j] = e[j] * inv;
    }
    __syncthreads();
    if (wave < 4) {
      float acc = 0.f;
#pragma unroll
      for (int j = 0; j < 4; ++j) {
        int i = lane + 64 * j;
        if (i <= t - 1) acc = fmaf(sR[i], sU[wave][i], acc);
      }
      acc = wred(acc);
      if (lane == 0) shF[wave] = lrelu(acc + m_in_b[r]);
    }
    __syncthreads();
    if (tid < 16) {
      int rp = tid >> 1, ch = tid & 1;
      i4 c; c.x = f2i(shF[2*ch]); c.y = f2i(shF[2*ch+1]); c.z = 0; c.w = t;
      store16(smC + rp * 512 + 2 * bid + ch, c);
    }

    // ---------- Phase C ----------
    MVP(m_h0_w, m_h0_b, 1, smCr, t, cCh, t)

    // ---------- Phase D (fires f3) ----------
    MVP(m_h1_w, m_h1_b, 1, cChr, t, fCh, t)

    // ---------- off-path: G work for row t-1 ----------
    if (t <= 254) {
      GWORK((t & 1), t, t - 1)
    }
    // ---------- off-path: collect own G (row=bid, fired at step bid+1) ----------
    if (t == bid + 2 && bid <= 253) {
      if (tid >= 256) {
        int u = tid - 256;
        const i4* gbase = gC + ((bid + 1) & 1) * 512;
        i4 c0 = poll16(gbase + 2 * u, bid + 1);
        i4 c1 = poll16(gbase + 2 * u + 1, bid + 1);
        G4.x = i2f(c0.x); G4.y = i2f(c0.y); G4.z = i2f(c1.x); G4.w = i2f(c1.y);
      }
    }
  }

  // ---- epilogue: z_256
  { i4 v = poll16(fChr + tid, 256); sX[2*tid] = i2f(v.x); sX[2*tid+1] = i2f(v.y); }
  __syncthreads();
  if (wave < 4) {
    float dM = 0.f;
#pragma unroll
    for (int q = 0; q < 4; ++q) {
      float4 xf = *(const float4*)(sX + 4 * lane + 256 * q);
      dM = fmaf(rMo[q].x, xf.x, dM); dM = fmaf(rMo[q].y, xf.y, dM);
      dM = fmaf(rMo[q].z, xf.z, dM); dM = fmaf(rMo[q].w, xf.w, dM);
    }
    dM = wred(dM);
    if (lane == 0) astore(Z + (size_t)256 * 1024 + r, z_prev + dM + mob_own);
  }
}

extern "C" void kernel_launch(void* const* d_in, const int* in_sizes, int n_in,
                              void* d_out, int out_size, void* d_ws, size_t ws_size,
                              hipStream_t stream) {
  (void)in_sizes; (void)n_in; (void)out_size; (void)ws_size;
  hipMemsetAsync(d_ws, 0, 315392, stream);  // bar + all chunk tag regions
  tcell<<<dim3(NBLK), dim3(NTHR), 0, stream>>>(
      (const float*)d_in[0],  (const float*)d_in[1],
      (const float*)d_in[2],  (const float*)d_in[3],  (const float*)d_in[4],
      (const float*)d_in[5],  (const float*)d_in[6],
      (const float*)d_in[7],  (const float*)d_in[8],
      (const float*)d_in[9],  (const float*)d_in[10],
      (const float*)d_in[11], (const float*)d_in[12],
      (const float*)d_in[13], (const float*)d_in[14],
      (const float*)d_in[15], (const float*)d_in[16],
      (const float*)d_in[17], (const float*)d_in[18],
      (const float*)d_in[19], (const float*)d_in[20],
      (float*)d_out, (float*)d_ws);
}